// Round 5
// baseline (251.151 us; speedup 1.0000x reference)
//
#include <hip/hip_runtime.h>
#include <hip/hip_bf16.h>
#include <math.h>

#define BB 8
#define NN 128
#define HN 256
#define HE 128
#define NH 8
#define DH 32
#define PP 8128
#define BP (BB*PP)   // 65024

typedef __hip_bfloat16 bf16;
typedef __hip_bfloat162 bf162;
typedef __attribute__((ext_vector_type(8))) short bf16x8;
typedef __attribute__((ext_vector_type(4))) float f32x4;

__device__ __forceinline__ float bf2f(bf16 x){ return __bfloat162float(x); }
__device__ __forceinline__ float bfraw2f(short u){
  return __uint_as_float(((unsigned)(unsigned short)u) << 16);
}

__device__ __forceinline__ float wave_sum(float v){
  #pragma unroll
  for (int off=32; off>=1; off>>=1) v += __shfl_xor(v, off, 64);
  return v;
}
__device__ __forceinline__ float g16_sum(float v){
  #pragma unroll
  for (int off=8; off>=1; off>>=1) v += __shfl_xor(v, off, 16);
  return v;
}

// triu pair index for N=128, i<j: p = i*(255-i)/2 + (j-i-1)
__device__ __forceinline__ int pair_idx(int a, int c){
  int i = a < c ? a : c;
  int j = a < c ? c : a;
  return ((i*(255 - i))>>1) + (j - i - 1);
}

// ---- workspace layout (float offsets). Only small canonical bias region used. ----
#define C_BEV  557312LL
#define C_BO   689672LL
#define C_BSK  821000LL
#define IOFF   822400LL
// intermediates (float offsets from IOFF)
#define I_NIN  0LL
#define I_Q    262144LL
#define I_K    524288LL
#define I_V    786432LL
#define I_ATTN 1048576LL
#define I_COMB 1310720LL
#define I_EA2  1572864LL   // [B][PP][8] f32 = 520192
#define I_XG   2093056LL   // [BP][128] bf16 = 4161536 float-slots
#define I_WT   14577664LL  // [256][128] bf16 = 16384 float-slots
#define I_WOB  14594048LL  // [512][256] bf16 = 65536 float-slots
#define I_WSKB 14659584LL  // [256][512] bf16 = 65536 float-slots
#define I_FLG  14725120LL

// role split for launch A
#define EDGEBLKS 4064
#define NODEBLKS 768
#define PREPBLKS 257

struct SrcPtrs { const void* p[16]; };
// p[]: 0 node,1 mask,2 Wqkv,3 bqkv,4 Wev,5 bev,6 Wea,7 bea,8 Wo,9 bo,10 Wsk,
//      11 bsk,12 gn,13 bn,14 ge,15 be

// per-block dtype detect: reads first 1024 u16 of node_feat (L2-broadcast, ~2KB)
__device__ __forceinline__ int detect_f32(const unsigned short* nodeRaw, int* sbad){
  if (threadIdx.x == 0) *sbad = 0;
  __syncthreads();
  int bad = 0;
  for (int i = threadIdx.x; i < 1024; i += 256){
    unsigned e = (nodeRaw[i] >> 7) & 0xFFu;
    if (e >= 194u) bad = 1;
  }
  if (bad) *sbad = 1;
  __syncthreads();
  return *sbad;
}

__device__ __forceinline__ float dualf(const void* p, long i, int f32){
  return f32 ? ((const float*)p)[i] : bfraw2f(((const short*)p)[i]);
}

// ================= Launch A: edge-LN | node-LN+QKV | prep, by blockIdx =========
__global__ __launch_bounds__(256) void kA(
    SrcPtrs sp, const void* __restrict__ edge_raw,
    float* __restrict__ nin_ws, float* __restrict__ q_ws, float* __restrict__ k_ws,
    float* __restrict__ v_ws, bf16* __restrict__ xg, float* __restrict__ ea2,
    bf16* __restrict__ Wt, bf16* __restrict__ WoB, bf16* __restrict__ WskB,
    float* __restrict__ ws, int* __restrict__ flags)
{
  __shared__ __align__(16) float smemF[3330];
  int* sbad = (int*)&smemF[3328];
  const int t = threadIdx.x;
  int bb = blockIdx.x;

  if (bb < EDGEBLKS){
    // ---------------- edge LN -> xg bf16, Wea GEMM + mask fold -> ea2 ----------
    const int f32 = detect_f32((const unsigned short*)sp.p[0], sbad);
    float* xlnS = smemF;            // [16][136]
    float* part = smemF + 2176;     // [128]
    float* WeaS = smemF + 2304;     // [128*8]
    {
      int i0 = t*4;
      if (f32){
        *reinterpret_cast<float4*>(&WeaS[i0]) =
            *reinterpret_cast<const float4*>((const float*)sp.p[6] + i0);
      } else {
        union { float2 f; short u[4]; } cv;
        cv.f = *reinterpret_cast<const float2*>((const short*)sp.p[6] + i0);
        WeaS[i0]   = bfraw2f(cv.u[0]); WeaS[i0+1] = bfraw2f(cv.u[1]);
        WeaS[i0+2] = bfraw2f(cv.u[2]); WeaS[i0+3] = bfraw2f(cv.u[3]);
      }
    }
    const int R0 = bb*16;
    const int b = R0 / PP;
    const int p0 = R0 - b*PP;
    {
      int r = t>>4, sub = t&15;
      long base = (long)(R0 + r)*HE + sub*8;
      float x[8];
      if (f32){
        const float* cef = (const float*)edge_raw + base;
        float4 a0 = *reinterpret_cast<const float4*>(cef);
        float4 a1 = *reinterpret_cast<const float4*>(cef + 4);
        x[0]=a0.x; x[1]=a0.y; x[2]=a0.z; x[3]=a0.w;
        x[4]=a1.x; x[5]=a1.y; x[6]=a1.z; x[7]=a1.w;
      } else {
        union { float4 f; short u[8]; } cv;
        cv.f = *reinterpret_cast<const float4*>((const bf16*)edge_raw + base);
        #pragma unroll
        for (int i=0;i<8;i++) x[i] = bfraw2f(cv.u[i]);
      }
      float s = 0.f;
      #pragma unroll
      for (int i=0;i<8;i++) s += x[i];
      s = g16_sum(s);
      float m = s*(1.0f/HE);
      float q = 0.f;
      #pragma unroll
      for (int i=0;i<8;i++){ float dd = x[i]-m; q += dd*dd; }
      q = g16_sum(q);
      float rstd = rsqrtf(fmaxf(q*(1.0f/HE), 0.f) + 1e-5f);
      #pragma unroll
      for (int i=0;i<8;i++){
        int c = sub*8 + i;
        float gev = dualf(sp.p[14], c, f32);
        float bev = dualf(sp.p[15], c, f32);
        xlnS[r*136 + c] = (x[i]-m)*rstd*gev + bev;
      }
    }
    __syncthreads();
    {
      int r = t>>4, c0 = (t&15)*8;
      union { float4 f; bf16 h[8]; } o;
      #pragma unroll
      for (int i=0;i<8;i++) o.h[i] = __float2bfloat16(xlnS[r*136 + c0+i]);
      *reinterpret_cast<float4*>(xg + (long)(R0 + r)*HE + c0) = o.f;
    }
    {
      const int c = t & 7, r = (t>>3) & 15, half = t>>7;
      const int pid = r*8 + c;
      float s = half ? 0.0f : dualf(sp.p[7], c, f32);
      const int k0 = half*64;
      #pragma unroll 8
      for (int k=k0; k<k0+64; k++) s = fmaf(xlnS[r*136 + k], WeaS[k*NH + c], s);
      if (half){ part[pid] = s; }
      __syncthreads();
      if (!half){
        s += part[pid];
        int p = p0 + r;
        float mk = dualf(sp.p[1], (long)b*PP + p, f32);
        ea2[((long)b*PP + p)*8 + c] = (mk != 0.0f) ? s : -9e15f;
      }
    }
    return;
  }
  bb -= EDGEBLKS;

  if (bb < NODEBLKS){
    // ---------------- node LN + QKV GEMM, column-split x3 ----------------------
    const int f32 = detect_f32((const unsigned short*)sp.p[0], sbad);
    float* xln = smemF;   // [4][256]
    const int wv = t>>6, lane = t&63;
    const int cb = bb % 3;           // 0=q, 1=k, 2=v
    const int g0 = (bb / 3) * 4;
    {
      int g = g0 + wv;
      float x[4];
      if (f32){
        const float* cn = (const float*)sp.p[0];
        #pragma unroll
        for (int i=0;i<4;i++) x[i] = cn[(long)g*HN + lane + 64*i];
      } else {
        const short* cn = (const short*)sp.p[0];
        #pragma unroll
        for (int i=0;i<4;i++) x[i] = bfraw2f(cn[(long)g*HN + lane + 64*i]);
      }
      float s = x[0]+x[1]+x[2]+x[3];
      s = wave_sum(s);
      float m = s * (1.0f/HN);
      float q = 0.f;
      #pragma unroll
      for (int i=0;i<4;i++){ float d = x[i]-m; q += d*d; }
      q = wave_sum(q);
      float rstd = rsqrtf(fmaxf(q*(1.0f/HN), 0.f) + 1e-5f);
      #pragma unroll
      for (int i=0;i<4;i++){
        int c = lane + 64*i;
        float gnv = dualf(sp.p[12], c, f32);
        float bnv = dualf(sp.p[13], c, f32);
        float y = (x[i]-m)*rstd*gnv + bnv;
        xln[wv*HN + c] = y;
        if (cb == 0) nin_ws[(long)g*HN + c] = y;
      }
    }
    __syncthreads();
    const int col = cb*256 + t;
    float acc[4];
    {
      float bb0 = dualf(sp.p[3], col, f32);
      #pragma unroll
      for (int r=0;r<4;r++) acc[r] = bb0;
    }
    if (f32){
      const float* W = (const float*)sp.p[2];
      for (int k=0;k<HN;k+=4){
        float4 xv[4];
        #pragma unroll
        for (int r=0;r<4;r++) xv[r] = *reinterpret_cast<const float4*>(&xln[r*HN + k]);
        #pragma unroll
        for (int kk=0;kk<4;kk++){
          float w = W[(long)(k+kk)*768 + col];
          #pragma unroll
          for (int r=0;r<4;r++) acc[r] = fmaf((&xv[r].x)[kk], w, acc[r]);
        }
      }
    } else {
      const short* W = (const short*)sp.p[2];
      for (int k=0;k<HN;k+=4){
        float4 xv[4];
        #pragma unroll
        for (int r=0;r<4;r++) xv[r] = *reinterpret_cast<const float4*>(&xln[r*HN + k]);
        #pragma unroll
        for (int kk=0;kk<4;kk++){
          float w = bfraw2f(W[(long)(k+kk)*768 + col]);
          #pragma unroll
          for (int r=0;r<4;r++) acc[r] = fmaf((&xv[r].x)[kk], w, acc[r]);
        }
      }
    }
    if (cb == 2){
      #pragma unroll
      for (int r=0;r<4;r++) v_ws[(long)(g0+r)*HN + t] = acc[r];
    } else {
      float* dstp = (cb == 0) ? q_ws : k_ws;
      const int h = t>>5, d = t&31;
      #pragma unroll
      for (int r=0;r<4;r++){
        int g = g0 + r;
        int b = g>>7, n = g&127;
        dstp[((b*NH + h)*NN + n)*DH + d] = acc[r];
      }
    }
    return;
  }
  bb -= NODEBLKS;

  // ---------------- prep: Wev^T | Wo/Wsk bf16 | biases+flag --------------------
  const int f32 = detect_f32((const unsigned short*)sp.p[0], sbad);
  if (bb < 128){
    int idx = bb*256 + t;   // < 32768 over Wev [128][256]
    float v = dualf(sp.p[4], idx, f32);
    Wt[(idx & 255)*128 + (idx >> 8)] = __float2bfloat16(v);
    return;
  }
  if (bb < 256){
    int o = (bb-128)*256 + t;   // < 32768 octets over Wo then Wsk
    const void* src = (o < 16384) ? sp.p[8] : sp.p[10];
    bf16* dw = (o < 16384) ? WoB : WskB;
    int lo = (o < 16384) ? o : o - 16384;
    if (f32){
      const float4* s4 = (const float4*)src;
      float4 a0 = s4[2*lo], a1 = s4[2*lo+1];
      union { float4 f; bf16 h[8]; } cv;
      cv.h[0]=__float2bfloat16(a0.x); cv.h[1]=__float2bfloat16(a0.y);
      cv.h[2]=__float2bfloat16(a0.z); cv.h[3]=__float2bfloat16(a0.w);
      cv.h[4]=__float2bfloat16(a1.x); cv.h[5]=__float2bfloat16(a1.y);
      cv.h[6]=__float2bfloat16(a1.z); cv.h[7]=__float2bfloat16(a1.w);
      *reinterpret_cast<float4*>(dw + lo*8) = cv.f;
    } else {
      *reinterpret_cast<float4*>(dw + lo*8) = ((const float4*)src)[lo];  // bit-exact
    }
    return;
  }
  // bb == 256: canonical biases for later launches + flag
  if (t == 0) flags[0] = f32;
  for (int i = t; i < 1024; i += 256){
    const void* src; float* dst; int li;
    if (i < 256){ src = sp.p[5];  dst = ws + C_BEV; li = i; }
    else if (i < 512){ src = sp.p[9];  dst = ws + C_BO;  li = i-256; }
    else { src = sp.p[11]; dst = ws + C_BSK; li = i-512; }
    dst[li] = dualf(src, li, f32);
  }
}

// ---------------- Launch B: fused graph attention, all heads per (b,n) --------
// attn[b,n,h,:] = sum_m p_hm * v[m] + (sum_m p_hm * xg[pr]) @ Wev_h + (sum p)*bev_h
// grid B*N = 1024 blocks (XCD-swizzled so each XCD owns one b); block 256 (32 lanes/head)
__global__ __launch_bounds__(256, 4) void k3_attn(
    const float* __restrict__ q_ws,   // [b][h][n][32]
    const float* __restrict__ k_ws,   // [b][h][n][32]
    const float* __restrict__ v_ws,   // [b][n][256]
    const bf16* __restrict__ xg,      // [b*PP][128]
    const float* __restrict__ ea2,    // [b][PP][8]
    const bf16* __restrict__ Wt,      // [256][128]  (Wev^T)
    const float* __restrict__ cbev,   // [256]
    float* __restrict__ attn)         // [b][n][256]
{
  __shared__ __align__(16) bf16  xgS[128][128];   // 32 KB gathered neighbor rows
  __shared__ __align__(16) float sS[8][128];      // 4 KB per-head S vectors
  const int t = threadIdx.x;
  const int bid = blockIdx.x;
  const int swz = (bid & 7)*128 + (bid >> 3);   // XCD j owns contiguous swz range = one b
  const int n = swz & 127, b = swz >> 7;
  const int h = t >> 5, ln = t & 31;

  // ---- Issue phase: all global loads go out before any compute/barrier ----
  float4 qv[8];
  const float* qb = q_ws + (((long)b*NH + h)*NN + n)*DH;
  #pragma unroll
  for (int d4=0; d4<8; d4++) qv[d4] = *reinterpret_cast<const float4*>(qb + d4*4);
  float eav[4];
  const float* eab = ea2 + (long)b*PP*8;
  #pragma unroll
  for (int j=0;j<4;j++){
    int m = ln + 32*j;
    int ms = (m == n) ? (m ^ 1) : m;
    eav[j] = eab[(long)pair_idx(n, ms)*8 + h];
  }
  const bf16* xgb = xg + (long)b*PP*HE;
  const int rowb = t >> 4, seg = t & 15;
  float4 xr[8];
  #pragma unroll
  for (int it=0; it<8; ++it){
    int row = it*16 + rowb;
    int ms = (row == n) ? (row ^ 1) : row;
    int pr = pair_idx(n, ms);
    xr[it] = *reinterpret_cast<const float4*>(xgb + (long)pr*HE + seg*8);
  }

  // ---- Phase B: fp32 QK dots + per-head softmax, no LDS, no barrier ----
  const float scale = 0.17677669529663687f;  // 32^-0.5
  const float* kb = k_ws + ((long)b*NH + h)*NN*DH;
  float l[4];
  float mx = -INFINITY;
  int valid = 0;
  #pragma unroll
  for (int j=0;j<4;j++){
    int m = ln + 32*j;
    const float* kr = kb + m*DH;
    float dot = 0.f;
    #pragma unroll
    for (int d4=0; d4<8; d4++){
      float4 kv = *reinterpret_cast<const float4*>(kr + d4*4);
      dot = fmaf(qv[d4].x, kv.x, dot);
      dot = fmaf(qv[d4].y, kv.y, dot);
      dot = fmaf(qv[d4].z, kv.z, dot);
      dot = fmaf(qv[d4].w, kv.w, dot);
    }
    bool self = (m == n);
    l[j] = self ? -INFINITY : fmaf(dot, scale, eav[j]);
    if (!self && eav[j] > -8.9e15f) valid = 1;
    mx = fmaxf(mx, l[j]);
  }
  #pragma unroll
  for (int off=16; off>=1; off>>=1) mx = fmaxf(mx, __shfl_xor(mx, off, 32));
  float e[4], s = 0.f;
  #pragma unroll
  for (int j=0;j<4;j++){ e[j] = __expf(l[j]-mx); s += e[j]; }
  float av = valid ? 1.f : 0.f;
  #pragma unroll
  for (int off=16; off>=1; off>>=1){
    s  += __shfl_xor(s,  off, 32);
    av += __shfl_xor(av, off, 32);
  }
  float inv = (av > 0.f) ? (1.0f/s) : 0.f;
  float pj0 = e[0]*inv, pj1 = e[1]*inv, pj2 = e[2]*inv, pj3 = e[3]*inv;

  // ---- Stage gathered xg rows to LDS (loads landed during Phase B) ----
  #pragma unroll
  for (int it=0; it<8; ++it){
    int row = it*16 + rowb;
    *reinterpret_cast<float4*>(&xgS[row][seg*8]) = xr[it];
  }
  __syncthreads();

  // ---- Phase C: branch-free p-weighted accumulate (p via shuffle broadcast) ----
  const float* vb = v_ws + (long)b*NN*HN + h*DH + ln;
  float S0=0.f,S1=0.f,S2=0.f,S3=0.f,T=0.f;
  #pragma unroll
  for (int j=0;j<4;j++){
    float pcur = (j==0) ? pj0 : (j==1) ? pj1 : (j==2) ? pj2 : pj3;
    #pragma unroll 2
    for (int mm=0; mm<32; mm+=4){
      #pragma unroll
      for (int i=0;i<4;i++){
        int m = j*32 + mm + i;
        float pm = __shfl(pcur, mm + i, 32);
        short4 xv = *reinterpret_cast<const short4*>(&xgS[m][ln*4]);
        S0 = fmaf(pm, bfraw2f(xv.x), S0);
        S1 = fmaf(pm, bfraw2f(xv.y), S1);
        S2 = fmaf(pm, bfraw2f(xv.z), S2);
        S3 = fmaf(pm, bfraw2f(xv.w), S3);
        T  = fmaf(pm, vb[m*HN], T);
      }
    }
  }
  {
    float4 sv; sv.x=S0; sv.y=S1; sv.z=S2; sv.w=S3;
    *reinterpret_cast<float4*>(&sS[h][ln*4]) = sv;
  }
  __syncthreads();

  // ---- Phase D: per-head 128x32 matvec with Wt (L2-resident), + bev + v-part ----
  float acc = T + ((av > 0.f) ? cbev[h*DH + ln] : 0.f);
  const bf16* wr = Wt + (h*DH + ln)*HE;
  #pragma unroll 4
  for (int k0=0;k0<128;k0+=8){
    float4 sa = *reinterpret_cast<const float4*>(&sS[h][k0]);
    float4 sb = *reinterpret_cast<const float4*>(&sS[h][k0+4]);
    bf16x8 wv = *reinterpret_cast<const bf16x8*>(wr + k0);
    acc = fmaf(sa.x, bfraw2f(wv[0]), acc);
    acc = fmaf(sa.y, bfraw2f(wv[1]), acc);
    acc = fmaf(sa.z, bfraw2f(wv[2]), acc);
    acc = fmaf(sa.w, bfraw2f(wv[3]), acc);
    acc = fmaf(sb.x, bfraw2f(wv[4]), acc);
    acc = fmaf(sb.y, bfraw2f(wv[5]), acc);
    acc = fmaf(sb.z, bfraw2f(wv[6]), acc);
    acc = fmaf(sb.w, bfraw2f(wv[7]), acc);
  }
  attn[((long)b*NN + n)*HN + h*DH + ln] = acc;
}

// ---------------- Launch C: fused Wo+GELU then Wsk+gate+residual --------------
// grid 256 = 256 rowgroups(4 rows); block 256 (one col each). comb lives in LDS.
__global__ __launch_bounds__(256) void k45(
    const float* __restrict__ nin_ws, const float* __restrict__ attn,
    const bf16* __restrict__ WoB, const float* __restrict__ cbo,
    const bf16* __restrict__ WskB, const float* __restrict__ cbsk,
    const void* __restrict__ cnode_raw, void* __restrict__ out,
    const int* __restrict__ flags)
{
  __shared__ __align__(16) float xc[4][512];
  __shared__ __align__(16) float cbS[4][256];
  const int t = threadIdx.x;
  const int g0 = blockIdx.x * 4;
  {
    int r = t>>6, c0 = (t&63)*8;
    const float* src = (c0 < 256) ? (nin_ws + (long)(g0+r)*HN + c0)
                                  : (attn + (long)(g0+r)*HN + (c0-256));
    float4 a0 = *reinterpret_cast<const float4*>(src);
    float4 a1 = *reinterpret_cast<const float4*>(src+4);
    *reinterpret_cast<float4*>(&xc[r][c0]) = a0;
    *reinterpret_cast<float4*>(&xc[r][c0+4]) = a1;
  }
  __syncthreads();
  const int col = t;
  float acc[4];
  {
    float bb0 = cbo[col];
    #pragma unroll
    for (int r=0;r<4;r++) acc[r] = bb0;
  }
  #pragma unroll 4
  for (int k=0;k<512;k++){
    float w = bf2f(WoB[k*HN + col]);   // coalesced 128B/wave, L2-hot
    #pragma unroll
    for (int r=0;r<4;r++) acc[r] = fmaf(xc[r][k], w, acc[r]);  // LDS broadcast
  }
  #pragma unroll
  for (int r=0;r<4;r++){
    float x = acc[r];
    cbS[r][col] = 0.5f*x*(1.0f + erff(x*0.7071067811865475f));
  }
  __syncthreads();
  float av[4], ag[4];
  {
    float bv = cbsk[col], bg = cbsk[col+256];
    #pragma unroll
    for (int r=0;r<4;r++){ av[r] = bv; ag[r] = bg; }
  }
  #pragma unroll 4
  for (int k=0;k<256;k++){
    float wv = bf2f(WskB[k*512 + col]);
    float wg = bf2f(WskB[k*512 + col + 256]);
    #pragma unroll
    for (int r=0;r<4;r++){
      float xr = cbS[r][k];   // LDS broadcast
      av[r] = fmaf(xr, wv, av[r]);
      ag[r] = fmaf(xr, wg, ag[r]);
    }
  }
  const int f32 = flags[0];
  #pragma unroll
  for (int r=0;r<4;r++){
    float gg = 1.0f/(1.0f + __expf(-ag[r]));
    long idx = (long)(g0+r)*HN + col;
    float nf = f32 ? ((const float*)cnode_raw)[idx]
                   : bfraw2f(((const short*)cnode_raw)[idx]);
    float res = nf*(1.0f - gg) + av[r]*gg;
    if (f32) ((float*)out)[idx] = res;
    else ((bf16*)out)[idx] = __float2bfloat16(res);
  }
}

extern "C" void kernel_launch(void* const* d_in, const int* in_sizes, int n_inputs,
                              void* d_out, int out_size, void* d_ws, size_t ws_size,
                              hipStream_t stream)
{
  float* ws = (float*)d_ws;
  float* base   = ws + IOFF;
  float* nin_ws  = base + I_NIN;
  float* q_ws    = base + I_Q;
  float* k_ws    = base + I_K;
  float* v_ws    = base + I_V;
  float* attn_ws = base + I_ATTN;
  float* ea2_ws  = base + I_EA2;
  bf16*  xg_ws   = (bf16*)(base + I_XG);
  bf16*  wt_ws   = (bf16*)(base + I_WT);
  bf16*  wob_ws  = (bf16*)(base + I_WOB);
  bf16*  wskb_ws = (bf16*)(base + I_WSKB);
  int*   flags   = (int*)(base + I_FLG);

  SrcPtrs sp;
  sp.p[0]  = d_in[0];   // node_feat
  sp.p[1]  = d_in[4];   // mask_valid
  sp.p[2]  = d_in[5];   // Wqkv
  sp.p[3]  = d_in[6];   // bqkv
  sp.p[4]  = d_in[7];   // Wev
  sp.p[5]  = d_in[8];   // bev
  sp.p[6]  = d_in[9];   // Wea
  sp.p[7]  = d_in[10];  // bea
  sp.p[8]  = d_in[11];  // Wo
  sp.p[9]  = d_in[12];  // bo
  sp.p[10] = d_in[13];  // Wsk
  sp.p[11] = d_in[14];  // bsk
  sp.p[12] = d_in[15];  // gn
  sp.p[13] = d_in[16];  // bn
  sp.p[14] = d_in[17];  // ge
  sp.p[15] = d_in[18];  // be

  kA<<<EDGEBLKS + NODEBLKS + PREPBLKS, 256, 0, stream>>>(
      sp, d_in[1], nin_ws, q_ws, k_ws, v_ws, xg_ws, ea2_ws,
      wt_ws, wob_ws, wskb_ws, ws, flags);
  k3_attn<<<BB*NN, 256, 0, stream>>>(q_ws, k_ws, v_ws, xg_ws, ea2_ws, wt_ws,
                                     ws + C_BEV, attn_ws);
  k45<<<256, 256, 0, stream>>>(nin_ws, attn_ws, wob_ws, ws + C_BO,
                               wskb_ws, ws + C_BSK, d_in[0], d_out, flags);
}

// Round 6
// 213.839 us; speedup vs baseline: 1.1745x; 1.1745x over previous
//
#include <hip/hip_runtime.h>
#include <hip/hip_bf16.h>
#include <math.h>

#define BB 8
#define NN 128
#define HN 256
#define HE 128
#define NH 8
#define DH 32
#define PP 8128
#define BP (BB*PP)   // 65024

typedef __hip_bfloat16 bf16;
typedef __hip_bfloat162 bf162;
typedef __attribute__((ext_vector_type(8))) short bf16x8;
typedef __attribute__((ext_vector_type(4))) float f32x4;

__device__ __forceinline__ float bf2f(bf16 x){ return __bfloat162float(x); }
__device__ __forceinline__ float bfraw2f(short u){
  return __uint_as_float(((unsigned)(unsigned short)u) << 16);
}

__device__ __forceinline__ float wave_sum(float v){
  #pragma unroll
  for (int off=32; off>=1; off>>=1) v += __shfl_xor(v, off, 64);
  return v;
}
__device__ __forceinline__ float g16_sum(float v){
  #pragma unroll
  for (int off=8; off>=1; off>>=1) v += __shfl_xor(v, off, 16);
  return v;
}

// triu pair index for N=128, i<j: p = i*(255-i)/2 + (j-i-1)
__device__ __forceinline__ int pair_idx(int a, int c){
  int i = a < c ? a : c;
  int j = a < c ? c : a;
  return ((i*(255 - i))>>1) + (j - i - 1);
}

// ---- workspace layout (float offsets). Only small canonical bias region used. ----
#define C_BEV  557312LL
#define C_BO   689672LL
#define C_BSK  821000LL
#define IOFF   822400LL
// intermediates (float offsets from IOFF)
#define I_NIN  0LL
#define I_Q    262144LL
#define I_K    524288LL
#define I_V    786432LL
#define I_ATTN 1048576LL
#define I_COMB 1310720LL
#define I_EA2  1572864LL   // [B][PP][8] f32 = 520192
#define I_XG   2093056LL   // [BP][128] bf16 = 4161536 float-slots
#define I_WT   14577664LL  // [256][128] bf16 = 16384 float-slots
#define I_WOB  14594048LL  // [512][256] bf16 = 65536 float-slots
#define I_WSKB 14659584LL  // [256][512] bf16 = 65536 float-slots
#define I_FLG  14725120LL

// role split for launch A
#define EDGEBLKS 4064
#define NODEBLKS 768
#define PREPBLKS 257

struct SrcPtrs { const void* p[16]; };
// p[]: 0 node,1 mask,2 Wqkv,3 bqkv,4 Wev,5 bev,6 Wea,7 bea,8 Wo,9 bo,10 Wsk,
//      11 bsk,12 gn,13 bn,14 ge,15 be

// per-block dtype detect: one ushort4 load/thread over first 1024 u16 (L1/L2-hot)
__device__ __forceinline__ int detect_f32(const unsigned short* nodeRaw, int* sbad){
  if (threadIdx.x == 0) *sbad = 0;
  __syncthreads();
  ushort4 v = reinterpret_cast<const ushort4*>(nodeRaw)[threadIdx.x];
  int bad = 0;
  if (((v.x >> 7) & 0xFFu) >= 194u) bad = 1;
  if (((v.y >> 7) & 0xFFu) >= 194u) bad = 1;
  if (((v.z >> 7) & 0xFFu) >= 194u) bad = 1;
  if (((v.w >> 7) & 0xFFu) >= 194u) bad = 1;
  if (bad) *sbad = 1;
  __syncthreads();
  return *sbad;
}

__device__ __forceinline__ float dualf(const void* p, long i, int f32){
  return f32 ? ((const float*)p)[i] : bfraw2f(((const short*)p)[i]);
}

// ================= Launch A: edge-LN | node-LN+QKV | prep, by blockIdx =========
__global__ __launch_bounds__(256) void kA(
    SrcPtrs sp, const void* __restrict__ edge_raw,
    float* __restrict__ nin_ws, float* __restrict__ q_ws, float* __restrict__ k_ws,
    float* __restrict__ v_ws, bf16* __restrict__ xg, float* __restrict__ ea2,
    bf16* __restrict__ Wt, bf16* __restrict__ WoB, bf16* __restrict__ WskB,
    float* __restrict__ ws, int* __restrict__ flags)
{
  __shared__ __align__(16) float smemF[3330];
  int* sbad = (int*)&smemF[3328];
  const int t = threadIdx.x;
  int bb = blockIdx.x;

  if (bb < EDGEBLKS){
    // ---------------- edge LN -> xg bf16, Wea GEMM + mask fold -> ea2 ----------
    const int f32 = detect_f32((const unsigned short*)sp.p[0], sbad);
    float* xlnS = smemF;            // [16][136]
    float* part = smemF + 2176;     // [128]
    float* WeaS = smemF + 2304;     // [128*8]
    {
      int i0 = t*4;
      if (f32){
        *reinterpret_cast<float4*>(&WeaS[i0]) =
            *reinterpret_cast<const float4*>((const float*)sp.p[6] + i0);
      } else {
        union { float2 f; short u[4]; } cv;
        cv.f = *reinterpret_cast<const float2*>((const short*)sp.p[6] + i0);
        WeaS[i0]   = bfraw2f(cv.u[0]); WeaS[i0+1] = bfraw2f(cv.u[1]);
        WeaS[i0+2] = bfraw2f(cv.u[2]); WeaS[i0+3] = bfraw2f(cv.u[3]);
      }
    }
    const int R0 = bb*16;
    const int b = R0 / PP;
    const int p0 = R0 - b*PP;
    {
      int r = t>>4, sub = t&15;
      long base = (long)(R0 + r)*HE + sub*8;
      float x[8];
      if (f32){
        const float* cef = (const float*)edge_raw + base;
        float4 a0 = *reinterpret_cast<const float4*>(cef);
        float4 a1 = *reinterpret_cast<const float4*>(cef + 4);
        x[0]=a0.x; x[1]=a0.y; x[2]=a0.z; x[3]=a0.w;
        x[4]=a1.x; x[5]=a1.y; x[6]=a1.z; x[7]=a1.w;
      } else {
        union { float4 f; short u[8]; } cv;
        cv.f = *reinterpret_cast<const float4*>((const bf16*)edge_raw + base);
        #pragma unroll
        for (int i=0;i<8;i++) x[i] = bfraw2f(cv.u[i]);
      }
      float s = 0.f;
      #pragma unroll
      for (int i=0;i<8;i++) s += x[i];
      s = g16_sum(s);
      float m = s*(1.0f/HE);
      float q = 0.f;
      #pragma unroll
      for (int i=0;i<8;i++){ float dd = x[i]-m; q += dd*dd; }
      q = g16_sum(q);
      float rstd = rsqrtf(fmaxf(q*(1.0f/HE), 0.f) + 1e-5f);
      float y[8];
      #pragma unroll
      for (int i=0;i<8;i++){
        int c = sub*8 + i;
        float gev = dualf(sp.p[14], c, f32);
        float bev = dualf(sp.p[15], c, f32);
        y[i] = (x[i]-m)*rstd*gev + bev;
      }
      // vectorized LDS store: 2x float4 instead of 8 scalar b32
      float4 y0; y0.x=y[0]; y0.y=y[1]; y0.z=y[2]; y0.w=y[3];
      float4 y1; y1.x=y[4]; y1.y=y[5]; y1.z=y[6]; y1.w=y[7];
      *reinterpret_cast<float4*>(&xlnS[r*136 + sub*8])     = y0;
      *reinterpret_cast<float4*>(&xlnS[r*136 + sub*8 + 4]) = y1;
    }
    __syncthreads();
    {
      int r = t>>4, c0 = (t&15)*8;
      union { float4 f; bf16 h[8]; } o;
      #pragma unroll
      for (int i=0;i<8;i++) o.h[i] = __float2bfloat16(xlnS[r*136 + c0+i]);
      *reinterpret_cast<float4*>(xg + (long)(R0 + r)*HE + c0) = o.f;
    }
    {
      const int c = t & 7, r = (t>>3) & 15, half = t>>7;
      const int pid = r*8 + c;
      float s = half ? 0.0f : dualf(sp.p[7], c, f32);
      const int k0 = half*64;
      #pragma unroll 8
      for (int k=k0; k<k0+64; k++) s = fmaf(xlnS[r*136 + k], WeaS[k*NH + c], s);
      if (half){ part[pid] = s; }
      __syncthreads();
      if (!half){
        s += part[pid];
        int p = p0 + r;
        float mk = dualf(sp.p[1], (long)b*PP + p, f32);
        ea2[((long)b*PP + p)*8 + c] = (mk != 0.0f) ? s : -9e15f;
      }
    }
    return;
  }
  bb -= EDGEBLKS;

  if (bb < NODEBLKS){
    // ---------------- node LN + QKV GEMM, column-split x3 ----------------------
    const int f32 = detect_f32((const unsigned short*)sp.p[0], sbad);
    float* xln = smemF;   // [4][256]
    const int wv = t>>6, lane = t&63;
    const int cb = bb % 3;           // 0=q, 1=k, 2=v
    const int g0 = (bb / 3) * 4;
    {
      int g = g0 + wv;
      float x[4];
      if (f32){
        const float* cn = (const float*)sp.p[0];
        #pragma unroll
        for (int i=0;i<4;i++) x[i] = cn[(long)g*HN + lane + 64*i];
      } else {
        const short* cn = (const short*)sp.p[0];
        #pragma unroll
        for (int i=0;i<4;i++) x[i] = bfraw2f(cn[(long)g*HN + lane + 64*i]);
      }
      float s = x[0]+x[1]+x[2]+x[3];
      s = wave_sum(s);
      float m = s * (1.0f/HN);
      float q = 0.f;
      #pragma unroll
      for (int i=0;i<4;i++){ float d = x[i]-m; q += d*d; }
      q = wave_sum(q);
      float rstd = rsqrtf(fmaxf(q*(1.0f/HN), 0.f) + 1e-5f);
      #pragma unroll
      for (int i=0;i<4;i++){
        int c = lane + 64*i;
        float gnv = dualf(sp.p[12], c, f32);
        float bnv = dualf(sp.p[13], c, f32);
        float y = (x[i]-m)*rstd*gnv + bnv;
        xln[wv*HN + c] = y;
        if (cb == 0) nin_ws[(long)g*HN + c] = y;
      }
    }
    __syncthreads();
    const int col = cb*256 + t;
    float acc[4];
    {
      float bb0 = dualf(sp.p[3], col, f32);
      #pragma unroll
      for (int r=0;r<4;r++) acc[r] = bb0;
    }
    if (f32){
      const float* W = (const float*)sp.p[2];
      for (int k=0;k<HN;k+=4){
        float4 xv[4];
        #pragma unroll
        for (int r=0;r<4;r++) xv[r] = *reinterpret_cast<const float4*>(&xln[r*HN + k]);
        #pragma unroll
        for (int kk=0;kk<4;kk++){
          float w = W[(long)(k+kk)*768 + col];
          #pragma unroll
          for (int r=0;r<4;r++) acc[r] = fmaf((&xv[r].x)[kk], w, acc[r]);
        }
      }
    } else {
      const short* W = (const short*)sp.p[2];
      for (int k=0;k<HN;k+=4){
        float4 xv[4];
        #pragma unroll
        for (int r=0;r<4;r++) xv[r] = *reinterpret_cast<const float4*>(&xln[r*HN + k]);
        #pragma unroll
        for (int kk=0;kk<4;kk++){
          float w = bfraw2f(W[(long)(k+kk)*768 + col]);
          #pragma unroll
          for (int r=0;r<4;r++) acc[r] = fmaf((&xv[r].x)[kk], w, acc[r]);
        }
      }
    }
    if (cb == 2){
      #pragma unroll
      for (int r=0;r<4;r++) v_ws[(long)(g0+r)*HN + t] = acc[r];
    } else {
      float* dstp = (cb == 0) ? q_ws : k_ws;
      const int h = t>>5, d = t&31;
      #pragma unroll
      for (int r=0;r<4;r++){
        int g = g0 + r;
        int b = g>>7, n = g&127;
        dstp[((b*NH + h)*NN + n)*DH + d] = acc[r];
      }
    }
    return;
  }
  bb -= NODEBLKS;

  // ---------------- prep: Wev^T | Wo/Wsk bf16 | biases+flag --------------------
  const int f32 = detect_f32((const unsigned short*)sp.p[0], sbad);
  if (bb < 128){
    int idx = bb*256 + t;   // < 32768 over Wev [128][256]
    float v = dualf(sp.p[4], idx, f32);
    Wt[(idx & 255)*128 + (idx >> 8)] = __float2bfloat16(v);
    return;
  }
  if (bb < 256){
    int o = (bb-128)*256 + t;   // < 32768 octets over Wo then Wsk
    const void* src = (o < 16384) ? sp.p[8] : sp.p[10];
    bf16* dw = (o < 16384) ? WoB : WskB;
    int lo = (o < 16384) ? o : o - 16384;
    if (f32){
      const float4* s4 = (const float4*)src;
      float4 a0 = s4[2*lo], a1 = s4[2*lo+1];
      union { float4 f; bf16 h[8]; } cv;
      cv.h[0]=__float2bfloat16(a0.x); cv.h[1]=__float2bfloat16(a0.y);
      cv.h[2]=__float2bfloat16(a0.z); cv.h[3]=__float2bfloat16(a0.w);
      cv.h[4]=__float2bfloat16(a1.x); cv.h[5]=__float2bfloat16(a1.y);
      cv.h[6]=__float2bfloat16(a1.z); cv.h[7]=__float2bfloat16(a1.w);
      *reinterpret_cast<float4*>(dw + lo*8) = cv.f;
    } else {
      *reinterpret_cast<float4*>(dw + lo*8) = ((const float4*)src)[lo];  // bit-exact
    }
    return;
  }
  // bb == 256: canonical biases for later launches + flag
  if (t == 0) flags[0] = f32;
  for (int i = t; i < 1024; i += 256){
    const void* src; float* dst; int li;
    if (i < 256){ src = sp.p[5];  dst = ws + C_BEV; li = i; }
    else if (i < 512){ src = sp.p[9];  dst = ws + C_BO;  li = i-256; }
    else { src = sp.p[11]; dst = ws + C_BSK; li = i-512; }
    dst[li] = dualf(src, li, f32);
  }
}

// ---------------- Launch B: fused graph attention, all heads per (b,n) --------
// attn[b,n,h,:] = sum_m p_hm * v[m] + (sum_m p_hm * xg[pr]) @ Wev_h + (sum p)*bev_h
// grid B*N = 1024 blocks (XCD-swizzled so each XCD owns one b); block 256 (32 lanes/head)
__global__ __launch_bounds__(256, 4) void k3_attn(
    const float* __restrict__ q_ws,   // [b][h][n][32]
    const float* __restrict__ k_ws,   // [b][h][n][32]
    const float* __restrict__ v_ws,   // [b][n][256]
    const bf16* __restrict__ xg,      // [b*PP][128]
    const float* __restrict__ ea2,    // [b][PP][8]
    const bf16* __restrict__ Wt,      // [256][128]  (Wev^T)
    const float* __restrict__ cbev,   // [256]
    float* __restrict__ attn)         // [b][n][256]
{
  __shared__ __align__(16) bf16  xgS[128][128];   // 32 KB gathered neighbor rows
  __shared__ __align__(16) float sS[8][128];      // 4 KB per-head S vectors
  const int t = threadIdx.x;
  const int bid = blockIdx.x;
  const int swz = (bid & 7)*128 + (bid >> 3);   // XCD j owns contiguous swz range = one b
  const int n = swz & 127, b = swz >> 7;
  const int h = t >> 5, ln = t & 31;

  // ---- Issue phase: all global loads go out before any compute/barrier ----
  float4 qv[8];
  const float* qb = q_ws + (((long)b*NH + h)*NN + n)*DH;
  #pragma unroll
  for (int d4=0; d4<8; d4++) qv[d4] = *reinterpret_cast<const float4*>(qb + d4*4);
  float eav[4];
  const float* eab = ea2 + (long)b*PP*8;
  #pragma unroll
  for (int j=0;j<4;j++){
    int m = ln + 32*j;
    int ms = (m == n) ? (m ^ 1) : m;
    eav[j] = eab[(long)pair_idx(n, ms)*8 + h];
  }
  const bf16* xgb = xg + (long)b*PP*HE;
  const int rowb = t >> 4, seg = t & 15;
  float4 xr[8];
  #pragma unroll
  for (int it=0; it<8; ++it){
    int row = it*16 + rowb;
    int ms = (row == n) ? (row ^ 1) : row;
    int pr = pair_idx(n, ms);
    xr[it] = *reinterpret_cast<const float4*>(xgb + (long)pr*HE + seg*8);
  }

  // ---- Phase B: fp32 QK dots + per-head softmax, no LDS, no barrier ----
  const float scale = 0.17677669529663687f;  // 32^-0.5
  const float* kb = k_ws + ((long)b*NH + h)*NN*DH;
  float l[4];
  float mx = -INFINITY;
  int valid = 0;
  #pragma unroll
  for (int j=0;j<4;j++){
    int m = ln + 32*j;
    const float* kr = kb + m*DH;
    float dot = 0.f;
    #pragma unroll
    for (int d4=0; d4<8; d4++){
      float4 kv = *reinterpret_cast<const float4*>(kr + d4*4);
      dot = fmaf(qv[d4].x, kv.x, dot);
      dot = fmaf(qv[d4].y, kv.y, dot);
      dot = fmaf(qv[d4].z, kv.z, dot);
      dot = fmaf(qv[d4].w, kv.w, dot);
    }
    bool self = (m == n);
    l[j] = self ? -INFINITY : fmaf(dot, scale, eav[j]);
    if (!self && eav[j] > -8.9e15f) valid = 1;
    mx = fmaxf(mx, l[j]);
  }
  #pragma unroll
  for (int off=16; off>=1; off>>=1) mx = fmaxf(mx, __shfl_xor(mx, off, 32));
  float e[4], s = 0.f;
  #pragma unroll
  for (int j=0;j<4;j++){ e[j] = __expf(l[j]-mx); s += e[j]; }
  float av = valid ? 1.f : 0.f;
  #pragma unroll
  for (int off=16; off>=1; off>>=1){
    s  += __shfl_xor(s,  off, 32);
    av += __shfl_xor(av, off, 32);
  }
  float inv = (av > 0.f) ? (1.0f/s) : 0.f;
  float pj0 = e[0]*inv, pj1 = e[1]*inv, pj2 = e[2]*inv, pj3 = e[3]*inv;

  // ---- Stage gathered xg rows to LDS (loads landed during Phase B) ----
  #pragma unroll
  for (int it=0; it<8; ++it){
    int row = it*16 + rowb;
    *reinterpret_cast<float4*>(&xgS[row][seg*8]) = xr[it];
  }
  __syncthreads();

  // ---- Phase C: branch-free p-weighted accumulate (p via shuffle broadcast) ----
  const float* vb = v_ws + (long)b*NN*HN + h*DH + ln;
  float S0=0.f,S1=0.f,S2=0.f,S3=0.f,T=0.f;
  #pragma unroll
  for (int j=0;j<4;j++){
    float pcur = (j==0) ? pj0 : (j==1) ? pj1 : (j==2) ? pj2 : pj3;
    #pragma unroll 2
    for (int mm=0; mm<32; mm+=4){
      #pragma unroll
      for (int i=0;i<4;i++){
        int m = j*32 + mm + i;
        float pm = __shfl(pcur, mm + i, 32);
        short4 xv = *reinterpret_cast<const short4*>(&xgS[m][ln*4]);
        S0 = fmaf(pm, bfraw2f(xv.x), S0);
        S1 = fmaf(pm, bfraw2f(xv.y), S1);
        S2 = fmaf(pm, bfraw2f(xv.z), S2);
        S3 = fmaf(pm, bfraw2f(xv.w), S3);
        T  = fmaf(pm, vb[m*HN], T);
      }
    }
  }
  {
    float4 sv; sv.x=S0; sv.y=S1; sv.z=S2; sv.w=S3;
    *reinterpret_cast<float4*>(&sS[h][ln*4]) = sv;
  }
  __syncthreads();

  // ---- Phase D: per-head 128x32 matvec with Wt (L2-resident), + bev + v-part ----
  float acc = T + ((av > 0.f) ? cbev[h*DH + ln] : 0.f);
  const bf16* wr = Wt + (h*DH + ln)*HE;
  #pragma unroll 4
  for (int k0=0;k0<128;k0+=8){
    float4 sa = *reinterpret_cast<const float4*>(&sS[h][k0]);
    float4 sb = *reinterpret_cast<const float4*>(&sS[h][k0+4]);
    bf16x8 wv = *reinterpret_cast<const bf16x8*>(wr + k0);
    acc = fmaf(sa.x, bfraw2f(wv[0]), acc);
    acc = fmaf(sa.y, bfraw2f(wv[1]), acc);
    acc = fmaf(sa.z, bfraw2f(wv[2]), acc);
    acc = fmaf(sa.w, bfraw2f(wv[3]), acc);
    acc = fmaf(sb.x, bfraw2f(wv[4]), acc);
    acc = fmaf(sb.y, bfraw2f(wv[5]), acc);
    acc = fmaf(sb.z, bfraw2f(wv[6]), acc);
    acc = fmaf(sb.w, bfraw2f(wv[7]), acc);
  }
  attn[((long)b*NN + n)*HN + h*DH + ln] = acc;
}

// ---------------- k4: concat(n_in, attn) @ Wo + bo, GELU ----------------
// grid 1024 = 256 rowgroups(4 rows) x 4 col-quarters(64); block 256 = 64 cols x 4 K-slices
__global__ __launch_bounds__(256) void k4_wo_gelu(
    const float* __restrict__ nin_ws, const float* __restrict__ attn,
    const bf16* __restrict__ WoB, const float* __restrict__ cbo,
    float* __restrict__ comb)
{
  __shared__ float xc[4][512];
  __shared__ float ps[3][4][64];
  const int t = threadIdx.x;
  const int g0 = (blockIdx.x >> 2) * 4;
  const int cq = blockIdx.x & 3;
  {
    int r = t>>6, c0 = (t&63)*8;
    const float* src = (c0 < 256) ? (nin_ws + (long)(g0+r)*HN + c0)
                                  : (attn + (long)(g0+r)*HN + (c0-256));
    float4 a0 = *reinterpret_cast<const float4*>(src);
    float4 a1 = *reinterpret_cast<const float4*>(src+4);
    *reinterpret_cast<float4*>(&xc[r][c0]) = a0;
    *reinterpret_cast<float4*>(&xc[r][c0+4]) = a1;
  }
  __syncthreads();
  const int cidx = t & 63, ks = t >> 6;
  const int col = cq*64 + cidx;
  float acc[4] = {0.f,0.f,0.f,0.f};
  const int k0 = ks*128;
  #pragma unroll 4
  for (int k=k0; k<k0+128; k++){
    float w = bf2f(WoB[k*HN + col]);
    #pragma unroll
    for (int r=0;r<4;r++) acc[r] = fmaf(xc[r][k], w, acc[r]);
  }
  if (ks){
    #pragma unroll
    for (int r=0;r<4;r++) ps[ks-1][r][cidx] = acc[r];
  }
  __syncthreads();
  if (!ks){
    float bb = cbo[col];
    #pragma unroll
    for (int r=0;r<4;r++){
      float x = acc[r] + bb + ps[0][r][cidx] + ps[1][r][cidx] + ps[2][r][cidx];
      comb[(long)(g0+r)*HN + col] = 0.5f*x*(1.0f + erff(x*0.7071067811865475f));
    }
  }
}

// ---------------- k5: comb @ Wsk + bsk, sigmoid gate + residual ----------------
// grid 1024 = 256 rowgroups(4 rows) x 4 col-quarters(64 val-cols); block 256 = 64 x 4 K-slices
__global__ __launch_bounds__(256) void k5_sk_gate(
    const float* __restrict__ comb, const void* __restrict__ cnode_raw,
    const bf16* __restrict__ WskB, const float* __restrict__ cbsk,
    void* __restrict__ out, const int* __restrict__ flags)
{
  __shared__ float xc[4][HN];
  __shared__ float psv[3][4][64];
  __shared__ float psg[3][4][64];
  const int t = threadIdx.x;
  const int g0 = (blockIdx.x >> 2) * 4;
  const int cq = blockIdx.x & 3;
  {
    int r = t>>6, c0 = (t&63)*4;
    *reinterpret_cast<float4*>(&xc[r][c0]) =
        *reinterpret_cast<const float4*>(comb + (long)(g0+r)*HN + c0);
  }
  __syncthreads();
  const int cidx = t & 63, ks = t >> 6;
  const int col = cq*64 + cidx;
  float av[4] = {0.f,0.f,0.f,0.f}, ag[4] = {0.f,0.f,0.f,0.f};
  const int k0 = ks*64;
  #pragma unroll 4
  for (int k=k0; k<k0+64; k++){
    float wv = bf2f(WskB[k*512 + col]);
    float wg = bf2f(WskB[k*512 + col + 256]);
    #pragma unroll
    for (int r=0;r<4;r++){
      float xr = xc[r][k];
      av[r] = fmaf(xr, wv, av[r]);
      ag[r] = fmaf(xr, wg, ag[r]);
    }
  }
  if (ks){
    #pragma unroll
    for (int r=0;r<4;r++){ psv[ks-1][r][cidx] = av[r]; psg[ks-1][r][cidx] = ag[r]; }
  }
  __syncthreads();
  if (!ks){
    const int f32 = flags[0];
    float bv = cbsk[col], bg = cbsk[col+256];
    #pragma unroll
    for (int r=0;r<4;r++){
      float v = av[r] + bv + psv[0][r][cidx] + psv[1][r][cidx] + psv[2][r][cidx];
      float g = ag[r] + bg + psg[0][r][cidx] + psg[1][r][cidx] + psg[2][r][cidx];
      float gg = 1.0f/(1.0f + __expf(-g));
      long idx = (long)(g0+r)*HN + col;
      float nf = f32 ? ((const float*)cnode_raw)[idx]
                     : bfraw2f(((const short*)cnode_raw)[idx]);
      float res = nf*(1.0f - gg) + v*gg;
      if (f32) ((float*)out)[idx] = res;
      else ((bf16*)out)[idx] = __float2bfloat16(res);
    }
  }
}

extern "C" void kernel_launch(void* const* d_in, const int* in_sizes, int n_inputs,
                              void* d_out, int out_size, void* d_ws, size_t ws_size,
                              hipStream_t stream)
{
  float* ws = (float*)d_ws;
  float* base   = ws + IOFF;
  float* nin_ws  = base + I_NIN;
  float* q_ws    = base + I_Q;
  float* k_ws    = base + I_K;
  float* v_ws    = base + I_V;
  float* attn_ws = base + I_ATTN;
  float* comb_ws = base + I_COMB;
  float* ea2_ws  = base + I_EA2;
  bf16*  xg_ws   = (bf16*)(base + I_XG);
  bf16*  wt_ws   = (bf16*)(base + I_WT);
  bf16*  wob_ws  = (bf16*)(base + I_WOB);
  bf16*  wskb_ws = (bf16*)(base + I_WSKB);
  int*   flags   = (int*)(base + I_FLG);

  SrcPtrs sp;
  sp.p[0]  = d_in[0];   // node_feat
  sp.p[1]  = d_in[4];   // mask_valid
  sp.p[2]  = d_in[5];   // Wqkv
  sp.p[3]  = d_in[6];   // bqkv
  sp.p[4]  = d_in[7];   // Wev
  sp.p[5]  = d_in[8];   // bev
  sp.p[6]  = d_in[9];   // Wea
  sp.p[7]  = d_in[10];  // bea
  sp.p[8]  = d_in[11];  // Wo
  sp.p[9]  = d_in[12];  // bo
  sp.p[10] = d_in[13];  // Wsk
  sp.p[11] = d_in[14];  // bsk
  sp.p[12] = d_in[15];  // gn
  sp.p[13] = d_in[16];  // bn
  sp.p[14] = d_in[17];  // ge
  sp.p[15] = d_in[18];  // be

  kA<<<EDGEBLKS + NODEBLKS + PREPBLKS, 256, 0, stream>>>(
      sp, d_in[1], nin_ws, q_ws, k_ws, v_ws, xg_ws, ea2_ws,
      wt_ws, wob_ws, wskb_ws, ws, flags);
  k3_attn<<<BB*NN, 256, 0, stream>>>(q_ws, k_ws, v_ws, xg_ws, ea2_ws, wt_ws,
                                     ws + C_BEV, attn_ws);
  k4_wo_gelu<<<1024, 256, 0, stream>>>(nin_ws, attn_ws, wob_ws, ws + C_BO, comb_ws);
  k5_sk_gate<<<1024, 256, 0, stream>>>(comb_ws, d_in[0], wskb_ws, ws + C_BSK,
                                       d_out, flags);
}